// Round 1
// baseline (2387.142 us; speedup 1.0000x reference)
//
#include <hip/hip_runtime.h>
#include <math.h>

namespace {

constexpr int S  = 2048;
constexpr int D  = 64;
constexpr int BH = 32;        // B*H = 4*8
constexpr int QT = 64;        // queries per block
constexpr int KT = 32;        // keys per tile
constexpr int QP = 68;        // padded row stride (floats) for Q tiles
constexpr int KP = 68;        // padded row stride for K/V/P tiles
constexpr float INV_T = 0.125f;   // 1/TEMPERATURE
constexpr float EPSF  = 1e-12f;
constexpr size_t PLANE = (size_t)BH * S * D;  // elements per (real|imag) output plane

__device__ __forceinline__ float f4get(const float4 v, int k) {
    return k == 0 ? v.x : (k == 1 ? v.y : (k == 2 ? v.z : v.w));
}

__global__ __launch_bounds__(256, 2)
void cv_attn(const float* __restrict__ qr_g, const float* __restrict__ qi_g,
             const float* __restrict__ kr_g, const float* __restrict__ ki_g,
             const float* __restrict__ vr_g, const float* __restrict__ vi_g,
             float* __restrict__ out)
{
    __shared__ float Qr[QT][QP];
    __shared__ float Qi[QT][QP];
    __shared__ float Kr[KT][KP];   // reused as Pr[t][q] after score phase
    __shared__ float Ki[KT][KP];   // reused as Pi[t][q]
    __shared__ float Vr[KT][KP];
    __shared__ float Vi[KT][KP];

    const int tid = (int)threadIdx.x;
    const int ty  = tid >> 4;          // 0..15
    const int tx  = tid & 15;          // 0..15
    const int bh  = (int)blockIdx.y;   // 0..31
    const int q0  = (int)blockIdx.x * QT;
    const size_t base = (size_t)bh * S * D;

    // ---- stage Q tile (pre-scaled by 1/T), natural [q][d] layout ----
    {
        const int c4 = tx * 4;
        #pragma unroll
        for (int r = ty; r < QT; r += 16) {
            const size_t g = base + (size_t)(q0 + r) * D + c4;
            float4 a = *(const float4*)(qr_g + g);
            float4 b = *(const float4*)(qi_g + g);
            a.x *= INV_T; a.y *= INV_T; a.z *= INV_T; a.w *= INV_T;
            b.x *= INV_T; b.y *= INV_T; b.z *= INV_T; b.w *= INV_T;
            *(float4*)&Qr[r][c4] = a;
            *(float4*)&Qi[r][c4] = b;
        }
    }

    const int qrow = ty * 4;           // this thread-group's 4 query rows
    float m_i[4], l_i[4];
    float Or[4][4], Oi[4][4];
    #pragma unroll
    for (int i = 0; i < 4; ++i) {
        m_i[i] = -INFINITY;
        l_i[i] = 0.0f;
        #pragma unroll
        for (int k = 0; k < 4; ++k) { Or[i][k] = 0.0f; Oi[i][k] = 0.0f; }
    }

    for (int kt = 0; kt < S / KT; ++kt) {
        const int k0 = kt * KT;

        __syncthreads();  // previous PV phase done reading P (=K bufs) and V
        {
            const int c4 = tx * 4;
            #pragma unroll
            for (int r = ty; r < KT; r += 16) {
                const size_t g = base + (size_t)(k0 + r) * D + c4;
                *(float4*)&Kr[r][c4] = *(const float4*)(kr_g + g);
                *(float4*)&Ki[r][c4] = *(const float4*)(ki_g + g);
                *(float4*)&Vr[r][c4] = *(const float4*)(vr_g + g);
                *(float4*)&Vi[r][c4] = *(const float4*)(vi_g + g);
            }
        }
        __syncthreads();

        // ---- score phase: z[i][j] for q = qrow+i, t = tx + 16*j ----
        float zr[4][2], zi[4][2];
        #pragma unroll
        for (int i = 0; i < 4; ++i) {
            zr[i][0] = 0.f; zr[i][1] = 0.f;
            zi[i][0] = 0.f; zi[i][1] = 0.f;
        }
        #pragma unroll 4
        for (int d = 0; d < D; d += 4) {
            const float4 kr0 = *(const float4*)&Kr[tx][d];
            const float4 ki0 = *(const float4*)&Ki[tx][d];
            const float4 kr1 = *(const float4*)&Kr[tx + 16][d];
            const float4 ki1 = *(const float4*)&Ki[tx + 16][d];
            #pragma unroll
            for (int i = 0; i < 4; ++i) {
                const float4 a4 = *(const float4*)&Qr[qrow + i][d];
                const float4 b4 = *(const float4*)&Qi[qrow + i][d];
                #pragma unroll
                for (int dd = 0; dd < 4; ++dd) {
                    const float ar = f4get(a4, dd), ai = f4get(b4, dd);
                    const float br0 = f4get(kr0, dd), bi0 = f4get(ki0, dd);
                    const float br1 = f4get(kr1, dd), bi1 = f4get(ki1, dd);
                    zr[i][0] += ar * br0 - ai * bi0;
                    zi[i][0] += ar * bi0 + ai * br0;
                    zr[i][1] += ar * br1 - ai * bi1;
                    zi[i][1] += ar * bi1 + ai * br1;
                }
            }
        }

        // ---- online softmax over magnitudes ----
        float mag[4][2];
        #pragma unroll
        for (int i = 0; i < 4; ++i) {
            mag[i][0] = sqrtf(zr[i][0] * zr[i][0] + zi[i][0] * zi[i][0]);
            mag[i][1] = sqrtf(zr[i][1] * zr[i][1] + zi[i][1] * zi[i][1]);
        }
        float mt[4];
        #pragma unroll
        for (int i = 0; i < 4; ++i) mt[i] = fmaxf(mag[i][0], mag[i][1]);
        #pragma unroll
        for (int off = 1; off < 16; off <<= 1) {
            #pragma unroll
            for (int i = 0; i < 4; ++i)
                mt[i] = fmaxf(mt[i], __shfl_xor(mt[i], off, 64));
        }
        float alpha[4], p[4][2], rs[4];
        #pragma unroll
        for (int i = 0; i < 4; ++i) {
            const float mnew = fmaxf(m_i[i], mt[i]);
            alpha[i] = __expf(m_i[i] - mnew);   // 0 on first tile (m = -inf)
            m_i[i] = mnew;
            p[i][0] = __expf(mag[i][0] - mnew);
            p[i][1] = __expf(mag[i][1] - mnew);
            rs[i] = p[i][0] + p[i][1];
        }
        #pragma unroll
        for (int off = 1; off < 16; off <<= 1) {
            #pragma unroll
            for (int i = 0; i < 4; ++i)
                rs[i] += __shfl_xor(rs[i], off, 64);
        }
        #pragma unroll
        for (int i = 0; i < 4; ++i) l_i[i] = l_i[i] * alpha[i] + rs[i];

        __syncthreads();  // all K reads done; safe to overwrite with P

        // P[t][q] = p * phase (phase = z / max(|z|, eps)), into K buffers
        #pragma unroll
        for (int j = 0; j < 2; ++j) {
            const int t = tx + 16 * j;
            #pragma unroll
            for (int i = 0; i < 4; ++i) {
                const float w = p[i][j] / fmaxf(mag[i][j], EPSF);
                Kr[t][qrow + i] = w * zr[i][j];
                Ki[t][qrow + i] = w * zi[i][j];
            }
        }
        __syncthreads();  // P visible to all waves

        // ---- PV phase: O[i][k], q = qrow+i, d = tx*4 + k ----
        #pragma unroll
        for (int i = 0; i < 4; ++i) {
            #pragma unroll
            for (int k = 0; k < 4; ++k) { Or[i][k] *= alpha[i]; Oi[i][k] *= alpha[i]; }
        }
        #pragma unroll 4
        for (int t = 0; t < KT; ++t) {
            const float4 pr4 = *(const float4*)&Kr[t][qrow];
            const float4 pi4 = *(const float4*)&Ki[t][qrow];
            const float4 vr4 = *(const float4*)&Vr[t][tx * 4];
            const float4 vi4 = *(const float4*)&Vi[t][tx * 4];
            #pragma unroll
            for (int i = 0; i < 4; ++i) {
                const float pr = f4get(pr4, i), pi = f4get(pi4, i);
                #pragma unroll
                for (int k = 0; k < 4; ++k) {
                    const float vr = f4get(vr4, k), vi = f4get(vi4, k);
                    Or[i][k] += pr * vr - pi * vi;
                    Oi[i][k] += pr * vi + pi * vr;
                }
            }
        }
    }

    // ---- epilogue: out = O / l, real plane then imag plane ----
    #pragma unroll
    for (int i = 0; i < 4; ++i) {
        const float linv = 1.0f / l_i[i];
        const size_t g = base + (size_t)(q0 + qrow + i) * D + tx * 4;
        float4 o;
        o.x = Or[i][0] * linv; o.y = Or[i][1] * linv;
        o.z = Or[i][2] * linv; o.w = Or[i][3] * linv;
        *(float4*)(out + g) = o;
        o.x = Oi[i][0] * linv; o.y = Oi[i][1] * linv;
        o.z = Oi[i][2] * linv; o.w = Oi[i][3] * linv;
        *(float4*)(out + PLANE + g) = o;
    }
}

} // namespace

extern "C" void kernel_launch(void* const* d_in, const int* in_sizes, int n_in,
                              void* d_out, int out_size, void* d_ws, size_t ws_size,
                              hipStream_t stream) {
    const float* qr = (const float*)d_in[0];
    const float* qi = (const float*)d_in[1];
    const float* kr = (const float*)d_in[2];
    const float* ki = (const float*)d_in[3];
    const float* vr = (const float*)d_in[4];
    const float* vi = (const float*)d_in[5];
    float* out = (float*)d_out;

    dim3 grid(S / QT, BH);   // (32, 32)
    cv_attn<<<grid, 256, 0, stream>>>(qr, qi, kr, ki, vr, vi, out);
}

// Round 2
// 386.699 us; speedup vs baseline: 6.1731x; 6.1731x over previous
//
#include <hip/hip_runtime.h>
#include <math.h>

typedef _Float16 half8  __attribute__((ext_vector_type(8)));
typedef _Float16 half4_t __attribute__((ext_vector_type(4)));
typedef float    floatx4 __attribute__((ext_vector_type(4)));

namespace {

constexpr int S  = 2048;
constexpr int D  = 64;
constexpr int BH = 32;
constexpr int QT = 64;     // queries per block (4 waves x 16)
constexpr int KT = 64;     // keys per tile
constexpr int ST = 72;     // LDS row stride in halves (144 B rows, 16B-aligned)
constexpr float INV_T = 0.125f;
constexpr size_t PLANE = (size_t)BH * S * D;

#define MFMA16(a, b, c) __builtin_amdgcn_mfma_f32_16x16x32_f16((a), (b), (c), 0, 0, 0)

__global__ __launch_bounds__(256, 2)
void cv_attn_mfma(const float* __restrict__ qr_g, const float* __restrict__ qi_g,
                  const float* __restrict__ kr_g, const float* __restrict__ ki_g,
                  const float* __restrict__ vr_g, const float* __restrict__ vi_g,
                  float* __restrict__ out)
{
    // K/V tiles shared; P buffers wave-private. All rows stride 72 halves.
    __shared__ __align__(16) _Float16 sm[4*64*ST + 4*2*16*ST];
    _Float16* const Kr = sm;                 // [t][d]
    _Float16* const Ki = Kr + 64*ST;
    _Float16* const Vr = Ki + 64*ST;         // [d][t] (transposed)
    _Float16* const Vi = Vr + 64*ST;
    _Float16* const Pb = Vi + 64*ST;

    const int tid  = (int)threadIdx.x;
    const int lane = tid & 63;
    const int wv   = tid >> 6;       // wave 0..3
    const int g    = lane >> 4;      // quad group 0..3
    const int m    = lane & 15;      // row-within-16 for A/B frags, col for C/D
    const int bh   = (int)blockIdx.y;
    const int q0   = (int)blockIdx.x * QT;
    const size_t base = (size_t)bh * S * D;

    _Float16* const Pr = Pb + wv * (2*16*ST);   // wave-private P (A-layout source)
    _Float16* const Pi = Pr + 16*ST;

    const int lofs = m*ST + g*8;     // common fragment offset (halves)

    // ---- Q fragments (A-layout: row=m, k=g*8+j), scaled by 1/T ----
    half8 aqr[2], aqi[2], aqin[2];
    {
        const size_t qoff = base + (size_t)(q0 + wv*16 + m) * D + g*8;
        #pragma unroll
        for (int kc = 0; kc < 2; ++kc) {
            float4 r0 = *(const float4*)(qr_g + qoff + kc*32);
            float4 r1 = *(const float4*)(qr_g + qoff + kc*32 + 4);
            float4 i0 = *(const float4*)(qi_g + qoff + kc*32);
            float4 i1 = *(const float4*)(qi_g + qoff + kc*32 + 4);
            half8 hr, hi;
            hr[0]=(_Float16)(r0.x*INV_T); hr[1]=(_Float16)(r0.y*INV_T);
            hr[2]=(_Float16)(r0.z*INV_T); hr[3]=(_Float16)(r0.w*INV_T);
            hr[4]=(_Float16)(r1.x*INV_T); hr[5]=(_Float16)(r1.y*INV_T);
            hr[6]=(_Float16)(r1.z*INV_T); hr[7]=(_Float16)(r1.w*INV_T);
            hi[0]=(_Float16)(i0.x*INV_T); hi[1]=(_Float16)(i0.y*INV_T);
            hi[2]=(_Float16)(i0.z*INV_T); hi[3]=(_Float16)(i0.w*INV_T);
            hi[4]=(_Float16)(i1.x*INV_T); hi[5]=(_Float16)(i1.y*INV_T);
            hi[6]=(_Float16)(i1.z*INV_T); hi[7]=(_Float16)(i1.w*INV_T);
            aqr[kc] = hr; aqi[kc] = hi; aqin[kc] = -hi;
        }
    }

    floatx4 Or[4], Oi[4];
    float m_run[4], l_run[4];
    #pragma unroll
    for (int r = 0; r < 4; ++r) {
        m_run[r] = -INFINITY; l_run[r] = 0.f;
    }
    #pragma unroll
    for (int nt = 0; nt < 4; ++nt) {
        Or[nt] = (floatx4){0.f,0.f,0.f,0.f};
        Oi[nt] = (floatx4){0.f,0.f,0.f,0.f};
    }

    for (int kt = 0; kt < S/KT; ++kt) {
        const int k0 = kt * KT;
        __syncthreads();   // previous tile's MFMA reads of K/V done

        if (wv < 2) {
            // stage one K plane, natural [t][d], f32 -> f16
            const float* src = (wv == 0 ? kr_g : ki_g) + base + (size_t)k0 * D;
            _Float16* dst = (wv == 0 ? Kr : Ki);
            #pragma unroll
            for (int it = 0; it < 16; ++it) {
                const int e  = it*64 + lane;
                const int t  = e >> 4;
                const int c4 = (e & 15) * 4;
                float4 v = *(const float4*)(src + t*64 + c4);
                half4_t h = {(_Float16)v.x, (_Float16)v.y, (_Float16)v.z, (_Float16)v.w};
                *(half4_t*)&dst[t*ST + c4] = h;
            }
        } else {
            // stage one V plane TRANSPOSED [d][t]; lane = d column (coalesced per-t)
            const float* src = (wv == 2 ? vr_g : vi_g) + base + (size_t)k0 * D;
            _Float16* dst = (wv == 2 ? Vr : Vi);
            #pragma unroll
            for (int t0 = 0; t0 < KT; t0 += 4) {
                float v0 = src[(t0+0)*64 + lane];
                float v1 = src[(t0+1)*64 + lane];
                float v2 = src[(t0+2)*64 + lane];
                float v3 = src[(t0+3)*64 + lane];
                half4_t h = {(_Float16)v0, (_Float16)v1, (_Float16)v2, (_Float16)v3};
                *(half4_t*)&dst[lane*ST + t0] = h;
            }
        }
        __syncthreads();   // tiles visible

        // ---- scores: Z[16q x 64t], 8 MFMAs per 16-wide key tile ----
        floatx4 Zr[4], Zi[4];
        #pragma unroll
        for (int nt = 0; nt < 4; ++nt) {
            floatx4 zr = (floatx4){0.f,0.f,0.f,0.f};
            floatx4 zi = (floatx4){0.f,0.f,0.f,0.f};
            #pragma unroll
            for (int kc = 0; kc < 2; ++kc) {
                const int o = nt*16*ST + lofs + kc*32;
                half8 bkr = *(const half8*)&Kr[o];
                half8 bki = *(const half8*)&Ki[o];
                zr = MFMA16(aqr[kc],  bkr, zr);
                zr = MFMA16(aqin[kc], bki, zr);   // Zr = QrKr' - QiKi'
                zi = MFMA16(aqr[kc],  bki, zi);
                zi = MFMA16(aqi[kc],  bkr, zi);   // Zi = QrKi' + QiKr'
            }
            Zr[nt] = zr; Zi[nt] = zi;
        }

        // ---- online softmax over magnitudes (C-layout: row=4g+r, col=nt*16+m) ----
        float mag[4][4];
        float mt[4] = {0.f, 0.f, 0.f, 0.f};   // mags >= 0, so 0 is a safe identity
        #pragma unroll
        for (int nt = 0; nt < 4; ++nt)
            #pragma unroll
            for (int r = 0; r < 4; ++r) {
                const float a = Zr[nt][r], b = Zi[nt][r];
                const float s = __builtin_amdgcn_sqrtf(a*a + b*b);
                mag[nt][r] = s;
                mt[r] = fmaxf(mt[r], s);
            }
        #pragma unroll
        for (int off = 1; off < 16; off <<= 1)
            #pragma unroll
            for (int r = 0; r < 4; ++r)
                mt[r] = fmaxf(mt[r], __shfl_xor(mt[r], off, 64));

        float alpha[4], rs[4];
        #pragma unroll
        for (int r = 0; r < 4; ++r) {
            const float mnew = fmaxf(m_run[r], mt[r]);
            alpha[r] = __expf(m_run[r] - mnew);   // 0 on first tile
            m_run[r] = mnew;
            rs[r] = 0.f;
        }

        // P = exp(mag-m)*z/|z| -> wave-private LDS (f16), layout [q][t]
        #pragma unroll
        for (int nt = 0; nt < 4; ++nt)
            #pragma unroll
            for (int r = 0; r < 4; ++r) {
                const float p = __expf(mag[nt][r] - m_run[r]);
                rs[r] += p;
                const float w = p * __builtin_amdgcn_rcpf(fmaxf(mag[nt][r], 1e-12f));
                Pr[(4*g + r)*ST + nt*16 + m] = (_Float16)(w * Zr[nt][r]);
                Pi[(4*g + r)*ST + nt*16 + m] = (_Float16)(w * Zi[nt][r]);
            }
        #pragma unroll
        for (int off = 1; off < 16; off <<= 1)
            #pragma unroll
            for (int r = 0; r < 4; ++r)
                rs[r] += __shfl_xor(rs[r], off, 64);
        #pragma unroll
        for (int r = 0; r < 4; ++r)
            l_run[r] = l_run[r]*alpha[r] + rs[r];

        // rescale O by alpha (flash update)
        #pragma unroll
        for (int nt = 0; nt < 4; ++nt)
            #pragma unroll
            for (int r = 0; r < 4; ++r) {
                Or[nt][r] *= alpha[r];
                Oi[nt][r] *= alpha[r];
            }

        // ---- PV: O += P * V (A = P from LDS, B = Vt rows = d) ----
        half8 apr[2], api[2], apin[2];
        #pragma unroll
        for (int kc = 0; kc < 2; ++kc) {
            apr[kc]  = *(const half8*)&Pr[lofs + kc*32];
            api[kc]  = *(const half8*)&Pi[lofs + kc*32];
            apin[kc] = -api[kc];
        }
        #pragma unroll
        for (int nt = 0; nt < 4; ++nt) {
            floatx4 ors = Or[nt], ois = Oi[nt];
            #pragma unroll
            for (int kc = 0; kc < 2; ++kc) {
                const int o = nt*16*ST + lofs + kc*32;
                half8 bvr = *(const half8*)&Vr[o];
                half8 bvi = *(const half8*)&Vi[o];
                ors = MFMA16(apr[kc],  bvr, ors);
                ors = MFMA16(apin[kc], bvi, ors);   // Or += PrV r - PiVi
                ois = MFMA16(apr[kc],  bvi, ois);
                ois = MFMA16(api[kc],  bvr, ois);   // Oi += PrVi + PiVr
            }
            Or[nt] = ors; Oi[nt] = ois;
        }
    }

    // ---- epilogue: out = O / l ----
    #pragma unroll
    for (int r = 0; r < 4; ++r) {
        const float linv = 1.0f / l_run[r];
        const size_t o = base + (size_t)(q0 + wv*16 + 4*g + r) * D + m;
        #pragma unroll
        for (int nt = 0; nt < 4; ++nt) {
            out[o + nt*16]         = Or[nt][r] * linv;
            out[PLANE + o + nt*16] = Oi[nt][r] * linv;
        }
    }
}

} // namespace

extern "C" void kernel_launch(void* const* d_in, const int* in_sizes, int n_in,
                              void* d_out, int out_size, void* d_ws, size_t ws_size,
                              hipStream_t stream) {
    const float* qr = (const float*)d_in[0];
    const float* qi = (const float*)d_in[1];
    const float* kr = (const float*)d_in[2];
    const float* ki = (const float*)d_in[3];
    const float* vr = (const float*)d_in[4];
    const float* vi = (const float*)d_in[5];
    float* out = (float*)d_out;

    dim3 grid(S / QT, BH);   // (32, 32) = 1024 blocks; 2 blocks/CU -> 2 clean rounds
    cv_attn_mfma<<<grid, 256, 0, stream>>>(qr, qi, kr, ki, vr, vi, out);
}

// Round 3
// 314.840 us; speedup vs baseline: 7.5821x; 1.2282x over previous
//
#include <hip/hip_runtime.h>
#include <math.h>

typedef _Float16 half8   __attribute__((ext_vector_type(8)));
typedef _Float16 half4_t __attribute__((ext_vector_type(4)));
typedef float    floatx4 __attribute__((ext_vector_type(4)));

namespace {

constexpr int S  = 2048;
constexpr int D  = 64;
constexpr int BH = 32;
constexpr int QT = 64;
constexpr int KT = 64;
constexpr int STP = 72;    // P row stride (halves); 144B rows keep b128 reads aligned
constexpr float INV_T = 0.125f;
constexpr size_t PLANE = (size_t)BH * S * D;   // f32 out plane elements
constexpr float MBIAS = 2.772588722239781f;    // 4*ln2: p = exp(mag)*2^-4 (cancels in O/l)

#define MFMA16(a, b, c) __builtin_amdgcn_mfma_f32_16x16x32_f16((a), (b), (c), 0, 0, 0)

typedef __attribute__((address_space(1))) const unsigned int guint;
typedef __attribute__((address_space(3))) unsigned int luint;

__device__ __forceinline__ void gl_lds16(const _Float16* g, _Float16* l) {
    __builtin_amdgcn_global_load_lds((guint*)g, (luint*)l, 16, 0, 0);
}

// ---- pre-pass: K planes -> f16, natural [bh][t][d], XOR-chunk swizzled by t&7 ----
__global__ __launch_bounds__(256)
void prep_k(const float* __restrict__ kr, const float* __restrict__ ki,
            _Float16* __restrict__ okr, _Float16* __restrict__ oki)
{
    const float* src = blockIdx.z ? ki : kr;
    _Float16*    dst = blockIdx.z ? oki : okr;
    const int bh = (int)blockIdx.y, t0 = (int)blockIdx.x * 64;
    const int r  = (int)threadIdx.x >> 2, cg = (int)threadIdx.x & 3;
    const size_t in = ((size_t)bh * S + t0 + r) * D + cg * 16;
    float4 f0 = *(const float4*)(src + in);
    float4 f1 = *(const float4*)(src + in + 4);
    float4 f2 = *(const float4*)(src + in + 8);
    float4 f3 = *(const float4*)(src + in + 12);
    half8 h0, h1;
    h0[0]=(_Float16)f0.x; h0[1]=(_Float16)f0.y; h0[2]=(_Float16)f0.z; h0[3]=(_Float16)f0.w;
    h0[4]=(_Float16)f1.x; h0[5]=(_Float16)f1.y; h0[6]=(_Float16)f1.z; h0[7]=(_Float16)f1.w;
    h1[0]=(_Float16)f2.x; h1[1]=(_Float16)f2.y; h1[2]=(_Float16)f2.z; h1[3]=(_Float16)f2.w;
    h1[4]=(_Float16)f3.x; h1[5]=(_Float16)f3.y; h1[6]=(_Float16)f3.z; h1[7]=(_Float16)f3.w;
    const int key = r & 7;
    const size_t ob = ((size_t)bh * S + t0 + r) * D;
    *(half8*)(dst + ob + ((cg*2    ) ^ key) * 8) = h0;
    *(half8*)(dst + ob + ((cg*2 + 1) ^ key) * 8) = h1;
}

// ---- pre-pass: V planes -> f16 TRANSPOSED [bh][d][s], per-64-window XOR swizzle by d&7 ----
__global__ __launch_bounds__(256)
void prep_v(const float* __restrict__ vr, const float* __restrict__ vi,
            _Float16* __restrict__ ovr, _Float16* __restrict__ ovi)
{
    __shared__ _Float16 tile[64][72];
    const float* src = blockIdx.z ? vi : vr;
    _Float16*    dst = blockIdx.z ? ovi : ovr;
    const int bh = (int)blockIdx.y, t0 = (int)blockIdx.x * 64;
    const int r  = (int)threadIdx.x >> 2, cg = (int)threadIdx.x & 3;
    const size_t in = ((size_t)bh * S + t0 + r) * D + cg * 16;
    #pragma unroll
    for (int j = 0; j < 4; ++j) {
        float4 f = *(const float4*)(src + in + j * 4);
        tile[cg*16 + j*4 + 0][r] = (_Float16)f.x;
        tile[cg*16 + j*4 + 1][r] = (_Float16)f.y;
        tile[cg*16 + j*4 + 2][r] = (_Float16)f.z;
        tile[cg*16 + j*4 + 3][r] = (_Float16)f.w;
    }
    __syncthreads();
    const int d = r;
    const int key = d & 7;
    const size_t ob = ((size_t)bh * D + d) * S + t0;
    half8 a = *(const half8*)&tile[d][cg*16];
    half8 b = *(const half8*)&tile[d][cg*16 + 8];
    *(half8*)(dst + ob + ((cg*2    ) ^ key) * 8) = a;
    *(half8*)(dst + ob + ((cg*2 + 1) ^ key) * 8) = b;
}

// ---- main: flash complex attention, f16 MFMA, async staging, max-free softmax ----
__global__ __launch_bounds__(256, 3)
void cv_attn_f16(const float* __restrict__ qr_g, const float* __restrict__ qi_g,
                 const _Float16* __restrict__ kh_r, const _Float16* __restrict__ kh_i,
                 const _Float16* __restrict__ vt_r, const _Float16* __restrict__ vt_i,
                 float* __restrict__ out)
{
    __shared__ __align__(16) _Float16 sm[4*64*64 + 4*2*16*STP];  // 32KB tiles + 18KB P
    _Float16* const Kr = sm;
    _Float16* const Ki = Kr + 64*64;
    _Float16* const Vr = Ki + 64*64;
    _Float16* const Vi = Vr + 64*64;
    _Float16* const Pb = Vi + 64*64;

    const int tid = (int)threadIdx.x, lane = tid & 63, wv = tid >> 6;
    const int g = lane >> 4, m = lane & 15;

    // XCD-aware decode: same bh stays on one XCD (K/V fit its 4MB L2)
    const int b   = (int)blockIdx.x;
    const int xcd = b & 7, y = b >> 3;
    const int qt  = y & 31, bh = xcd + 8 * (y >> 5);
    const int q0  = qt * QT;
    const size_t base = (size_t)bh * S * D;

    _Float16* const Pr = Pb + wv * (2*16*STP);
    _Float16* const Pi = Pr + 16*STP;

    const int ck0 = ((g    ) ^ (m & 7)) * 8;   // swizzled chunk offsets (B-frag rows = m)
    const int ck1 = ((g + 4) ^ (m & 7)) * 8;
    const int rb  = m * 64;
    const int pofs = m * STP + g * 8;

    // Q fragments (A-layout: row=m, k=g*8+j + kc*32), scaled by 1/T
    half8 aqr[2], aqi[2], aqin[2];
    {
        const size_t qoff = base + (size_t)(q0 + wv*16 + m) * D + g*8;
        #pragma unroll
        for (int kc = 0; kc < 2; ++kc) {
            float4 r0 = *(const float4*)(qr_g + qoff + kc*32);
            float4 r1 = *(const float4*)(qr_g + qoff + kc*32 + 4);
            float4 i0 = *(const float4*)(qi_g + qoff + kc*32);
            float4 i1 = *(const float4*)(qi_g + qoff + kc*32 + 4);
            half8 hr, hi;
            hr[0]=(_Float16)(r0.x*INV_T); hr[1]=(_Float16)(r0.y*INV_T);
            hr[2]=(_Float16)(r0.z*INV_T); hr[3]=(_Float16)(r0.w*INV_T);
            hr[4]=(_Float16)(r1.x*INV_T); hr[5]=(_Float16)(r1.y*INV_T);
            hr[6]=(_Float16)(r1.z*INV_T); hr[7]=(_Float16)(r1.w*INV_T);
            hi[0]=(_Float16)(i0.x*INV_T); hi[1]=(_Float16)(i0.y*INV_T);
            hi[2]=(_Float16)(i0.z*INV_T); hi[3]=(_Float16)(i0.w*INV_T);
            hi[4]=(_Float16)(i1.x*INV_T); hi[5]=(_Float16)(i1.y*INV_T);
            hi[6]=(_Float16)(i1.z*INV_T); hi[7]=(_Float16)(i1.w*INV_T);
            aqr[kc] = hr; aqi[kc] = hi; aqin[kc] = -hi;
        }
    }

    floatx4 Or[4], Oi[4];
    float l_run[4] = {0.f, 0.f, 0.f, 0.f};
    #pragma unroll
    for (int nt = 0; nt < 4; ++nt) {
        Or[nt] = (floatx4){0.f,0.f,0.f,0.f};
        Oi[nt] = (floatx4){0.f,0.f,0.f,0.f};
    }

    for (int kt = 0; kt < S/KT; ++kt) {
        const int k0 = kt * KT;
        __syncthreads();   // previous tile's reads of K/V done

        // async stage: wave w stages one plane (8 x 1KB, verbatim pre-swizzled)
        if (wv < 2) {
            const _Float16* src = (wv ? kh_i : kh_r) + ((size_t)bh*S + k0)*D + lane*8;
            _Float16* dst = (wv ? Ki : Kr);
            #pragma unroll
            for (int i = 0; i < 8; ++i)
                gl_lds16(src + i*512, dst + i*512);
        } else {
            const _Float16* src = (wv == 2 ? vt_r : vt_i)
                                + ((size_t)bh*D + (lane>>3))*S + k0 + (lane&7)*8;
            _Float16* dst = (wv == 2 ? Vr : Vi);
            #pragma unroll
            for (int i = 0; i < 8; ++i)
                gl_lds16(src + (size_t)i*8*S, dst + i*512);
        }
        __syncthreads();   // vmcnt drained by barrier; tiles visible

        // ---- scores: Z[16q x 64t] ----
        floatx4 Zr[4], Zi[4];
        #pragma unroll
        for (int nt = 0; nt < 4; ++nt) {
            const int o = nt*16*64 + rb;
            half8 bkr0 = *(const half8*)&Kr[o + ck0];
            half8 bki0 = *(const half8*)&Ki[o + ck0];
            half8 bkr1 = *(const half8*)&Kr[o + ck1];
            half8 bki1 = *(const half8*)&Ki[o + ck1];
            floatx4 zr = (floatx4){0.f,0.f,0.f,0.f};
            floatx4 zi = (floatx4){0.f,0.f,0.f,0.f};
            zr = MFMA16(aqr[0],  bkr0, zr);
            zr = MFMA16(aqin[0], bki0, zr);
            zr = MFMA16(aqr[1],  bkr1, zr);
            zr = MFMA16(aqin[1], bki1, zr);
            zi = MFMA16(aqr[0],  bki0, zi);
            zi = MFMA16(aqi[0],  bkr0, zi);
            zi = MFMA16(aqr[1],  bki1, zi);
            zi = MFMA16(aqi[1],  bkr1, zi);
            Zr[nt] = zr; Zi[nt] = zi;
        }

        // ---- max-free softmax: p = exp(|z|)*2^-4; P = p * z/|z| (f16) ----
        #pragma unroll
        for (int nt = 0; nt < 4; ++nt) {
            #pragma unroll
            for (int r = 0; r < 4; ++r) {
                const float zr = Zr[nt][r], zi = Zi[nt][r];
                const float s2  = fmaf(zr, zr, fmaf(zi, zi, 1e-24f));
                const float inv = __builtin_amdgcn_rsqf(s2);
                const float mag = s2 * inv;
                const float p   = __expf(mag - MBIAS);
                l_run[r] += p;
                const float w = p * inv;
                Pr[(4*g + r)*STP + nt*16 + m] = (_Float16)(w * zr);
                Pi[(4*g + r)*STP + nt*16 + m] = (_Float16)(w * zi);
            }
        }
        // P is wave-private: no barrier needed (compiler inserts lgkm waits)

        // ---- PV: O += P * V ----
        half8 apr[2], api[2], apin[2];
        apr[0] = *(const half8*)&Pr[pofs];      apr[1] = *(const half8*)&Pr[pofs + 32];
        api[0] = *(const half8*)&Pi[pofs];      api[1] = *(const half8*)&Pi[pofs + 32];
        apin[0] = -api[0]; apin[1] = -api[1];
        #pragma unroll
        for (int nt = 0; nt < 4; ++nt) {
            const int o = nt*16*64 + rb;
            half8 bvr0 = *(const half8*)&Vr[o + ck0];
            half8 bvi0 = *(const half8*)&Vi[o + ck0];
            half8 bvr1 = *(const half8*)&Vr[o + ck1];
            half8 bvi1 = *(const half8*)&Vi[o + ck1];
            floatx4 or_ = Or[nt], oi_ = Oi[nt];
            or_ = MFMA16(apr[0],  bvr0, or_);
            or_ = MFMA16(apin[0], bvi0, or_);
            or_ = MFMA16(apr[1],  bvr1, or_);
            or_ = MFMA16(apin[1], bvi1, or_);
            oi_ = MFMA16(apr[0],  bvi0, oi_);
            oi_ = MFMA16(api[0],  bvr0, oi_);
            oi_ = MFMA16(apr[1],  bvi1, oi_);
            oi_ = MFMA16(api[1],  bvr1, oi_);
            Or[nt] = or_; Oi[nt] = oi_;
        }
    }

    // ---- deferred l reduction (plain sum commutes under max-free scheme) ----
    #pragma unroll
    for (int off = 1; off < 16; off <<= 1)
        #pragma unroll
        for (int r = 0; r < 4; ++r)
            l_run[r] += __shfl_xor(l_run[r], off, 64);

    #pragma unroll
    for (int r = 0; r < 4; ++r) {
        const float linv = 1.0f / l_run[r];
        const size_t o = base + (size_t)(q0 + wv*16 + 4*g + r) * D + m;
        #pragma unroll
        for (int nt = 0; nt < 4; ++nt) {
            out[o + nt*16]         = Or[nt][r] * linv;
            out[PLANE + o + nt*16] = Oi[nt][r] * linv;
        }
    }
}

// ---------------- round-2 fallback (used only if ws too small) ----------------
constexpr int ST2 = 72;
__global__ __launch_bounds__(256, 2)
void cv_attn_mfma(const float* __restrict__ qr_g, const float* __restrict__ qi_g,
                  const float* __restrict__ kr_g, const float* __restrict__ ki_g,
                  const float* __restrict__ vr_g, const float* __restrict__ vi_g,
                  float* __restrict__ out)
{
    __shared__ __align__(16) _Float16 sm[4*64*ST2 + 4*2*16*ST2];
    _Float16* const Kr = sm;
    _Float16* const Ki = Kr + 64*ST2;
    _Float16* const Vr = Ki + 64*ST2;
    _Float16* const Vi = Vr + 64*ST2;
    _Float16* const Pb = Vi + 64*ST2;

    const int tid = (int)threadIdx.x, lane = tid & 63, wv = tid >> 6;
    const int g = lane >> 4, m = lane & 15;
    const int bh = (int)blockIdx.y;
    const int q0 = (int)blockIdx.x * QT;
    const size_t base = (size_t)bh * S * D;
    _Float16* const Pr = Pb + wv * (2*16*ST2);
    _Float16* const Pi = Pr + 16*ST2;
    const int lofs = m*ST2 + g*8;

    half8 aqr[2], aqi[2], aqin[2];
    {
        const size_t qoff = base + (size_t)(q0 + wv*16 + m) * D + g*8;
        #pragma unroll
        for (int kc = 0; kc < 2; ++kc) {
            float4 r0 = *(const float4*)(qr_g + qoff + kc*32);
            float4 r1 = *(const float4*)(qr_g + qoff + kc*32 + 4);
            float4 i0 = *(const float4*)(qi_g + qoff + kc*32);
            float4 i1 = *(const float4*)(qi_g + qoff + kc*32 + 4);
            half8 hr, hi;
            hr[0]=(_Float16)(r0.x*INV_T); hr[1]=(_Float16)(r0.y*INV_T);
            hr[2]=(_Float16)(r0.z*INV_T); hr[3]=(_Float16)(r0.w*INV_T);
            hr[4]=(_Float16)(r1.x*INV_T); hr[5]=(_Float16)(r1.y*INV_T);
            hr[6]=(_Float16)(r1.z*INV_T); hr[7]=(_Float16)(r1.w*INV_T);
            hi[0]=(_Float16)(i0.x*INV_T); hi[1]=(_Float16)(i0.y*INV_T);
            hi[2]=(_Float16)(i0.z*INV_T); hi[3]=(_Float16)(i0.w*INV_T);
            hi[4]=(_Float16)(i1.x*INV_T); hi[5]=(_Float16)(i1.y*INV_T);
            hi[6]=(_Float16)(i1.z*INV_T); hi[7]=(_Float16)(i1.w*INV_T);
            aqr[kc] = hr; aqi[kc] = hi; aqin[kc] = -hi;
        }
    }

    floatx4 Or[4], Oi[4];
    float m_run[4], l_run[4];
    #pragma unroll
    for (int r = 0; r < 4; ++r) { m_run[r] = -INFINITY; l_run[r] = 0.f; }
    #pragma unroll
    for (int nt = 0; nt < 4; ++nt) {
        Or[nt] = (floatx4){0.f,0.f,0.f,0.f};
        Oi[nt] = (floatx4){0.f,0.f,0.f,0.f};
    }

    for (int kt = 0; kt < S/KT; ++kt) {
        const int k0 = kt * KT;
        __syncthreads();
        if (wv < 2) {
            const float* src = (wv == 0 ? kr_g : ki_g) + base + (size_t)k0 * D;
            _Float16* dst = (wv == 0 ? Kr : Ki);
            #pragma unroll
            for (int it = 0; it < 16; ++it) {
                const int e = it*64 + lane, t = e >> 4, c4 = (e & 15) * 4;
                float4 v = *(const float4*)(src + t*64 + c4);
                half4_t h = {(_Float16)v.x, (_Float16)v.y, (_Float16)v.z, (_Float16)v.w};
                *(half4_t*)&dst[t*ST2 + c4] = h;
            }
        } else {
            const float* src = (wv == 2 ? vr_g : vi_g) + base + (size_t)k0 * D;
            _Float16* dst = (wv == 2 ? Vr : Vi);
            #pragma unroll
            for (int t0 = 0; t0 < KT; t0 += 4) {
                float v0 = src[(t0+0)*64 + lane];
                float v1 = src[(t0+1)*64 + lane];
                float v2 = src[(t0+2)*64 + lane];
                float v3 = src[(t0+3)*64 + lane];
                half4_t h = {(_Float16)v0, (_Float16)v1, (_Float16)v2, (_Float16)v3};
                *(half4_t*)&dst[lane*ST2 + t0] = h;
            }
        }
        __syncthreads();

        floatx4 Zr[4], Zi[4];
        #pragma unroll
        for (int nt = 0; nt < 4; ++nt) {
            floatx4 zr = (floatx4){0.f,0.f,0.f,0.f};
            floatx4 zi = (floatx4){0.f,0.f,0.f,0.f};
            #pragma unroll
            for (int kc = 0; kc < 2; ++kc) {
                const int o = nt*16*ST2 + lofs + kc*32;
                half8 bkr = *(const half8*)&Kr[o];
                half8 bki = *(const half8*)&Ki[o];
                zr = MFMA16(aqr[kc],  bkr, zr);
                zr = MFMA16(aqin[kc], bki, zr);
                zi = MFMA16(aqr[kc],  bki, zi);
                zi = MFMA16(aqi[kc],  bkr, zi);
            }
            Zr[nt] = zr; Zi[nt] = zi;
        }

        float mag[4][4], mt[4] = {0.f,0.f,0.f,0.f};
        #pragma unroll
        for (int nt = 0; nt < 4; ++nt)
            #pragma unroll
            for (int r = 0; r < 4; ++r) {
                const float a = Zr[nt][r], bz = Zi[nt][r];
                const float s = __builtin_amdgcn_sqrtf(a*a + bz*bz);
                mag[nt][r] = s; mt[r] = fmaxf(mt[r], s);
            }
        #pragma unroll
        for (int off = 1; off < 16; off <<= 1)
            #pragma unroll
            for (int r = 0; r < 4; ++r)
                mt[r] = fmaxf(mt[r], __shfl_xor(mt[r], off, 64));

        float alpha[4], rs[4];
        #pragma unroll
        for (int r = 0; r < 4; ++r) {
            const float mnew = fmaxf(m_run[r], mt[r]);
            alpha[r] = __expf(m_run[r] - mnew);
            m_run[r] = mnew; rs[r] = 0.f;
        }
        #pragma unroll
        for (int nt = 0; nt < 4; ++nt)
            #pragma unroll
            for (int r = 0; r < 4; ++r) {
                const float p = __expf(mag[nt][r] - m_run[r]);
                rs[r] += p;
                const float w = p * __builtin_amdgcn_rcpf(fmaxf(mag[nt][r], 1e-12f));
                Pr[(4*g + r)*ST2 + nt*16 + m] = (_Float16)(w * Zr[nt][r]);
                Pi[(4*g + r)*ST2 + nt*16 + m] = (_Float16)(w * Zi[nt][r]);
            }
        #pragma unroll
        for (int off = 1; off < 16; off <<= 1)
            #pragma unroll
            for (int r = 0; r < 4; ++r)
                rs[r] += __shfl_xor(rs[r], off, 64);
        #pragma unroll
        for (int r = 0; r < 4; ++r) l_run[r] = l_run[r]*alpha[r] + rs[r];

        #pragma unroll
        for (int nt = 0; nt < 4; ++nt)
            #pragma unroll
            for (int r = 0; r < 4; ++r) { Or[nt][r] *= alpha[r]; Oi[nt][r] *= alpha[r]; }

        half8 apr[2], api[2], apin[2];
        #pragma unroll
        for (int kc = 0; kc < 2; ++kc) {
            apr[kc]  = *(const half8*)&Pr[lofs + kc*32];
            api[kc]  = *(const half8*)&Pi[lofs + kc*32];
            apin[kc] = -api[kc];
        }
        #pragma unroll
        for (int nt = 0; nt < 4; ++nt) {
            floatx4 ors = Or[nt], ois = Oi[nt];
            #pragma unroll
            for (int kc = 0; kc < 2; ++kc) {
                const int o = nt*16*ST2 + lofs + kc*32;
                half8 bvr = *(const half8*)&Vr[o];
                half8 bvi = *(const half8*)&Vi[o];
                ors = MFMA16(apr[kc],  bvr, ors);
                ors = MFMA16(apin[kc], bvi, ors);
                ois = MFMA16(apr[kc],  bvi, ois);
                ois = MFMA16(api[kc],  bvr, ois);
            }
            Or[nt] = ors; Oi[nt] = ois;
        }
    }

    #pragma unroll
    for (int r = 0; r < 4; ++r) {
        const float linv = 1.0f / l_run[r];
        const size_t o = base + (size_t)(q0 + wv*16 + 4*g + r) * D + m;
        #pragma unroll
        for (int nt = 0; nt < 4; ++nt) {
            out[o + nt*16]         = Or[nt][r] * linv;
            out[PLANE + o + nt*16] = Oi[nt][r] * linv;
        }
    }
}

} // namespace

extern "C" void kernel_launch(void* const* d_in, const int* in_sizes, int n_in,
                              void* d_out, int out_size, void* d_ws, size_t ws_size,
                              hipStream_t stream) {
    const float* qr = (const float*)d_in[0];
    const float* qi = (const float*)d_in[1];
    const float* kr = (const float*)d_in[2];
    const float* ki = (const float*)d_in[3];
    const float* vr = (const float*)d_in[4];
    const float* vi = (const float*)d_in[5];
    float* out = (float*)d_out;

    const size_t PH = (size_t)BH * S * D;            // halves per ws plane
    const size_t need = 4 * PH * sizeof(_Float16);   // 33.6 MB
    if (ws_size >= need) {
        _Float16* khr = (_Float16*)d_ws;
        _Float16* khi = khr + PH;
        _Float16* vtr = khi + PH;
        _Float16* vti = vtr + PH;
        prep_k<<<dim3(32, 32, 2), 256, 0, stream>>>(kr, ki, khr, khi);
        prep_v<<<dim3(32, 32, 2), 256, 0, stream>>>(vr, vi, vtr, vti);
        cv_attn_f16<<<1024, 256, 0, stream>>>(qr, qi, khr, khi, vtr, vti, out);
    } else {
        cv_attn_mfma<<<dim3(32, 32), 256, 0, stream>>>(qr, qi, kr, ki, vr, vi, out);
    }
}